// Round 1
// baseline (5674.539 us; speedup 1.0000x reference)
//
#include <hip/hip_runtime.h>
#include <math.h>

namespace {

constexpr int kIn  = 128;
constexpr int kH1  = 512;
constexpr int kH2  = 300;
constexpr int kOut = 10;
constexpr float kEps = 1e-5f;

__device__ __forceinline__ void atomAddF(float* p, float v) {
  unsafeAtomicAdd(p, v);  // HW global_atomic_add_f32, no CAS loop
}

// ---------------- degree / normalization ----------------
__global__ void k_init_deg(float* __restrict__ deg, int n) {
  int i = blockIdx.x * blockDim.x + threadIdx.x;
  if (i < n) deg[i] = 1.0f;  // self-loop weight
}

__global__ void k_deg_edges(float* __restrict__ deg, const int* __restrict__ ei,
                            const float* __restrict__ w, int nE) {
  int i = blockIdx.x * blockDim.x + threadIdx.x;
  if (i < nE) atomAddF(&deg[ei[nE + i]], w[i]);  // target = col = ei[1][i]
}

__global__ void k_dis(float* __restrict__ deg, int n) {
  int i = blockIdx.x * blockDim.x + threadIdx.x;
  if (i < n) deg[i] = rsqrtf(deg[i]);  // deg >= 1 always (self loop)
}

// ---------------- propagate: out[col] += X[row] * norm ----------------
// one thread = one edge x 4 dims (float4 gather, 4 atomics)
template<int D>
__global__ void k_propagate(const float* __restrict__ X, const int* __restrict__ ei,
                            const float* __restrict__ w, const float* __restrict__ dis,
                            float* __restrict__ out, int nE, int nN) {
  constexpr int D4 = D / 4;
  int idx = blockIdx.x * blockDim.x + threadIdx.x;
  int e = idx / D4;
  int p = idx - e * D4;
  if (e >= nE + nN) return;
  int r, c;
  float nw;
  if (e < nE) {
    r = ei[e];
    c = ei[nE + e];
    nw = dis[r] * w[e] * dis[c];
  } else {
    r = c = e - nE;  // self loop, weight 1
    float d = dis[r];
    nw = d * d;
  }
  const float4 xv = *reinterpret_cast<const float4*>(X + (size_t)r * D + p * 4);
  float* o = out + (size_t)c * D + p * 4;
  atomAddF(o + 0, xv.x * nw);
  atomAddF(o + 1, xv.y * nw);
  atomAddF(o + 2, xv.z * nw);
  atomAddF(o + 3, xv.w * nw);
}

// ---------------- SGEMM: C[M,Nn] = A[M,K] @ B[K,Nn] (+bias) ----------------
// 128x128 block tile, 8x8 per thread, BK=16, 256 threads
template<int BM, int BN, int BK, int TM, int TN>
__global__ __launch_bounds__(256) void k_sgemm(const float* __restrict__ A,
    const float* __restrict__ B, const float* __restrict__ bias,
    float* __restrict__ C, int M, int Nn, int K) {
  __shared__ __align__(16) float As[BK][BM];  // A stored transposed
  __shared__ __align__(16) float Bs[BK][BN];
  const int tid = threadIdx.x;
  const int tx = tid % (BN / TN);  // 0..15
  const int ty = tid / (BN / TN);  // 0..15
  const int m0 = blockIdx.x * BM;
  const int n0 = blockIdx.y * BN;

  const int ar = tid >> 1;         // 0..127, A tile row
  const int ak = (tid & 1) * 8;    // 0 or 8
  const int bk = tid >> 4;         // 0..15,  B tile row (k)
  const int bc = (tid & 15) * 8;   // 0..120, B tile col

  const bool a_ok = (m0 + ar) < M;
  const float* Ap = A + (size_t)(m0 + ar) * K + ak;
  const float* Bp = B + (size_t)bk * Nn + n0 + bc;

  float acc[TM][TN] = {};

  for (int k0 = 0; k0 < K; k0 += BK) {
    float av[8], bv[8];
    if (a_ok) {
      float4 a0 = *reinterpret_cast<const float4*>(Ap + k0);
      float4 a1 = *reinterpret_cast<const float4*>(Ap + k0 + 4);
      av[0] = a0.x; av[1] = a0.y; av[2] = a0.z; av[3] = a0.w;
      av[4] = a1.x; av[5] = a1.y; av[6] = a1.z; av[7] = a1.w;
    } else {
#pragma unroll
      for (int j = 0; j < 8; ++j) av[j] = 0.f;
    }
    if (n0 + bc + 8 <= Nn) {
      float4 b0 = *reinterpret_cast<const float4*>(Bp + (size_t)k0 * Nn);
      float4 b1 = *reinterpret_cast<const float4*>(Bp + (size_t)k0 * Nn + 4);
      bv[0] = b0.x; bv[1] = b0.y; bv[2] = b0.z; bv[3] = b0.w;
      bv[4] = b1.x; bv[5] = b1.y; bv[6] = b1.z; bv[7] = b1.w;
    } else {
#pragma unroll
      for (int j = 0; j < 8; ++j)
        bv[j] = (n0 + bc + j < Nn) ? Bp[(size_t)k0 * Nn + j] : 0.f;
    }
    __syncthreads();  // protect previous tile's reads
#pragma unroll
    for (int j = 0; j < 8; ++j) As[ak + j][ar] = av[j];
    *reinterpret_cast<float4*>(&Bs[bk][bc])     = make_float4(bv[0], bv[1], bv[2], bv[3]);
    *reinterpret_cast<float4*>(&Bs[bk][bc + 4]) = make_float4(bv[4], bv[5], bv[6], bv[7]);
    __syncthreads();
#pragma unroll
    for (int kk = 0; kk < BK; ++kk) {
      float4 a0 = *reinterpret_cast<const float4*>(&As[kk][ty * TM]);
      float4 a1 = *reinterpret_cast<const float4*>(&As[kk][ty * TM + 4]);
      float4 b0 = *reinterpret_cast<const float4*>(&Bs[kk][tx * TN]);
      float4 b1 = *reinterpret_cast<const float4*>(&Bs[kk][tx * TN + 4]);
      float a[8] = {a0.x, a0.y, a0.z, a0.w, a1.x, a1.y, a1.z, a1.w};
      float b[8] = {b0.x, b0.y, b0.z, b0.w, b1.x, b1.y, b1.z, b1.w};
#pragma unroll
      for (int i = 0; i < TM; ++i)
#pragma unroll
        for (int j = 0; j < TN; ++j)
          acc[i][j] = fmaf(a[i], b[j], acc[i][j]);
    }
  }

#pragma unroll
  for (int i = 0; i < TM; ++i) {
    int m = m0 + ty * TM + i;
    if (m >= M) continue;
    float* Cp = C + (size_t)m * Nn;
#pragma unroll
    for (int j = 0; j < TN; ++j) {
      int nn = n0 + tx * TN + j;
      if (nn < Nn) {
        float v = acc[i][j];
        if (bias) v += bias[nn];
        Cp[nn] = v;
      }
    }
  }
}

// ---------------- BatchNorm ----------------
__global__ void k_bn_stats(const float* __restrict__ H, float* __restrict__ s1,
                           float* __restrict__ s2, int n, int C, int rpb) {
  int r0 = blockIdx.x * rpb;
  int r1 = r0 + rpb;
  if (r1 > n) r1 = n;
  for (int c = threadIdx.x; c < C; c += blockDim.x) {
    float a = 0.f, b = 0.f;
    for (int r = r0; r < r1; ++r) {
      float v = H[(size_t)r * C + c];
      a += v;
      b = fmaf(v, v, b);
    }
    atomAddF(&s1[c], a);
    atomAddF(&s2[c], b);
  }
}

__global__ void k_bn_finalize(const float* __restrict__ s1, const float* __restrict__ s2,
                              const float* __restrict__ g, const float* __restrict__ beta,
                              float* __restrict__ scale, float* __restrict__ shift,
                              int C, float invN) {
  int c = blockIdx.x * blockDim.x + threadIdx.x;
  if (c >= C) return;
  float mean = s1[c] * invN;
  float var = fmaxf(s2[c] * invN - mean * mean, 0.f);  // biased var
  float sc = g[c] * rsqrtf(var + kEps);
  scale[c] = sc;
  shift[c] = beta[c] - mean * sc;
}

template<int C>  // C power of 2
__global__ void k_bn_apply_relu(float* __restrict__ H, const float* __restrict__ scale,
                                const float* __restrict__ shift, int total4) {
  int i = blockIdx.x * blockDim.x + threadIdx.x;
  if (i >= total4) return;
  float4 v = reinterpret_cast<float4*>(H)[i];
  int c = (i * 4) & (C - 1);
  v.x = fmaxf(fmaf(v.x, scale[c],     shift[c]),     0.f);
  v.y = fmaxf(fmaf(v.y, scale[c + 1], shift[c + 1]), 0.f);
  v.z = fmaxf(fmaf(v.z, scale[c + 2], shift[c + 2]), 0.f);
  v.w = fmaxf(fmaf(v.w, scale[c + 3], shift[c + 3]), 0.f);
  reinterpret_cast<float4*>(H)[i] = v;
}

// ---------------- head: BN2-apply + relu + @Wl + bl + relu + log_softmax ----------------
__global__ __launch_bounds__(256) void k_head(const float* __restrict__ H,
    const float* __restrict__ scale, const float* __restrict__ shift,
    const float* __restrict__ Wl, const float* __restrict__ bl,
    float* __restrict__ out, int n) {
  __shared__ float sW[kH2 * kOut];
  __shared__ float sScale[kH2], sShift[kH2];
  for (int i = threadIdx.x; i < kH2 * kOut; i += blockDim.x) sW[i] = Wl[i];
  for (int i = threadIdx.x; i < kH2; i += blockDim.x) {
    sScale[i] = scale[i];
    sShift[i] = shift[i];
  }
  __syncthreads();
  float blv[kOut];
#pragma unroll
  for (int j = 0; j < kOut; ++j) blv[j] = bl[j];
  const int lane = threadIdx.x & 63;
  const int wid = (blockIdx.x * blockDim.x + threadIdx.x) >> 6;
  const int nw  = (gridDim.x * blockDim.x) >> 6;
  for (int node = wid; node < n; node += nw) {
    const float* hrow = H + (size_t)node * kH2;
    float acc[kOut] = {};
    for (int k = lane; k < kH2; k += 64) {
      float v = fmaxf(fmaf(hrow[k], sScale[k], sShift[k]), 0.f);
      const float* wr = sW + k * kOut;
#pragma unroll
      for (int j = 0; j < kOut; ++j) acc[j] = fmaf(v, wr[j], acc[j]);
    }
#pragma unroll
    for (int j = 0; j < kOut; ++j) {
      float v = acc[j];
      for (int off = 32; off > 0; off >>= 1) v += __shfl_down(v, off);
      acc[j] = v;  // valid on lane 0
    }
    if (lane == 0) {
      float vv[kOut], m = -1e30f;
#pragma unroll
      for (int j = 0; j < kOut; ++j) {
        vv[j] = fmaxf(acc[j] + blv[j], 0.f);
        m = fmaxf(m, vv[j]);
      }
      float s = 0.f;
#pragma unroll
      for (int j = 0; j < kOut; ++j) s += expf(vv[j] - m);
      float lse = m + logf(s);
      float* o = out + (size_t)node * kOut;
#pragma unroll
      for (int j = 0; j < kOut; ++j) o[j] = vv[j] - lse;
    }
  }
}

}  // namespace

extern "C" void kernel_launch(void* const* d_in, const int* in_sizes, int n_in,
                              void* d_out, int out_size, void* d_ws, size_t ws_size,
                              hipStream_t stream) {
  const float* x   = (const float*)d_in[0];
  const int*   ei  = (const int*)d_in[1];
  const float* ew  = (const float*)d_in[2];
  const float* W1  = (const float*)d_in[3];
  const float* b1  = (const float*)d_in[4];
  const float* g1  = (const float*)d_in[5];
  const float* be1 = (const float*)d_in[6];
  const float* W2  = (const float*)d_in[7];
  // d_in[8] = b2: provably cancelled by BatchNorm mean-subtraction — skipped
  const float* g2  = (const float*)d_in[9];
  const float* be2 = (const float*)d_in[10];
  const float* Wl  = (const float*)d_in[11];
  const float* bl  = (const float*)d_in[12];
  float* out = (float*)d_out;
  float* ws  = (float*)d_ws;

  const int n = in_sizes[0] / kIn;  // 50000
  const int e = in_sizes[1] / 2;    // 800000

  // workspace layout (floats); peak ~162.6 MB with aliasing:
  //   dis: [0, 50048)
  //   t2 (N x 300): [50048, 15050048)    -- agg1 (N x 128) aliases its head
  //   h1 (N x 512): [15050048, 40650048) -- agg2 (N x 300) aliases its head
  //   stats: [40650048, +4096)
  float* dis  = ws;
  float* t2   = ws + 50048;
  float* agg1 = t2;
  float* h1   = ws + 15050048;
  float* agg2 = h1;
  float* st   = ws + 40650048;
  float* s1a = st,        *s2a = st + 512,  *sc1 = st + 1024, *sh1 = st + 1536;
  float* s1b = st + 2048, *s2b = st + 2560, *sc2 = st + 3072, *sh2 = st + 3584;

  constexpr int TPB = 256;

  // gcn_norm
  k_init_deg<<<(n + TPB - 1) / TPB, TPB, 0, stream>>>(dis, n);
  k_deg_edges<<<(e + TPB - 1) / TPB, TPB, 0, stream>>>(dis, ei, ew, e);
  k_dis<<<(n + TPB - 1) / TPB, TPB, 0, stream>>>(dis, n);

  // layer 1: propagate(x) @ W1 (+b1), BN, relu
  hipMemsetAsync(agg1, 0, (size_t)n * kIn * sizeof(float), stream);
  {
    long long tot = (long long)(e + n) * (kIn / 4);
    k_propagate<kIn><<<(int)((tot + TPB - 1) / TPB), TPB, 0, stream>>>(x, ei, ew, dis, agg1, e, n);
  }
  {
    dim3 g((n + 127) / 128, (kH1 + 127) / 128);
    k_sgemm<128, 128, 16, 8, 8><<<g, 256, 0, stream>>>(agg1, W1, b1, h1, n, kH1, kIn);
  }
  hipMemsetAsync(st, 0, 4096 * sizeof(float), stream);
  k_bn_stats<<<512, 256, 0, stream>>>(h1, s1a, s2a, n, kH1, (n + 511) / 512);
  k_bn_finalize<<<(kH1 + 255) / 256, 256, 0, stream>>>(s1a, s2a, g1, be1, sc1, sh1, kH1, 1.0f / n);
  k_bn_apply_relu<kH1><<<((n * (kH1 / 4)) + TPB - 1) / TPB, TPB, 0, stream>>>(h1, sc1, sh1, n * (kH1 / 4));

  // layer 2: propagate(h1 @ W2), BN (apply fused into head), relu
  {
    dim3 g((n + 127) / 128, (kH2 + 127) / 128);
    k_sgemm<128, 128, 16, 8, 8><<<g, 256, 0, stream>>>(h1, W2, nullptr, t2, n, kH2, kH1);
  }
  hipMemsetAsync(agg2, 0, (size_t)n * kH2 * sizeof(float), stream);
  {
    long long tot = (long long)(e + n) * (kH2 / 4);
    k_propagate<kH2><<<(int)((tot + TPB - 1) / TPB), TPB, 0, stream>>>(t2, ei, ew, dis, agg2, e, n);
  }
  k_bn_stats<<<512, 256, 0, stream>>>(agg2, s1b, s2b, n, kH2, (n + 511) / 512);
  k_bn_finalize<<<(kH2 + 255) / 256, 256, 0, stream>>>(s1b, s2b, g2, be2, sc2, sh2, kH2, 1.0f / n);

  // head: BN2-apply + relu + @Wl + bl + relu + log_softmax
  k_head<<<1024, 256, 0, stream>>>(agg2, sc2, sh2, Wl, bl, out, n);
}

// Round 2
// 920.716 us; speedup vs baseline: 6.1632x; 6.1632x over previous
//
#include <hip/hip_runtime.h>
#include <math.h>

namespace {

constexpr int kIn  = 128;
constexpr int kH1  = 512;
constexpr int kH2  = 300;
constexpr int kOut = 10;
constexpr float kEps = 1e-5f;

__device__ __forceinline__ void atomAddF(float* p, float v) {
  unsafeAtomicAdd(p, v);  // HW global_atomic_add_f32
}

__device__ __forceinline__ unsigned short f2bf(float f) {  // RNE f32->bf16
  unsigned u = __builtin_bit_cast(unsigned, f);
  unsigned r = u + 0x7fffu + ((u >> 16) & 1u);
  return (unsigned short)(r >> 16);
}

__device__ __forceinline__ float4 unpack_bf4(uint2 q) {
  float4 r;
  r.x = __builtin_bit_cast(float, (q.x & 0xffffu) << 16);
  r.y = __builtin_bit_cast(float, q.x & 0xffff0000u);
  r.z = __builtin_bit_cast(float, (q.y & 0xffffu) << 16);
  r.w = __builtin_bit_cast(float, q.y & 0xffff0000u);
  return r;
}

// ---------------- degree / counting ----------------
__global__ void k_init(float* __restrict__ deg, int* __restrict__ cnt, int n) {
  int i = blockIdx.x * blockDim.x + threadIdx.x;
  if (i < n) { deg[i] = 1.0f; cnt[i] = 0; }  // self-loop weight 1
}

__global__ void k_deg_cnt(float* __restrict__ deg, int* __restrict__ cnt,
                          const int* __restrict__ ei, const float* __restrict__ w, int nE) {
  int i = blockIdx.x * blockDim.x + threadIdx.x;
  if (i < nE) {
    int c = ei[nE + i];  // target
    atomAddF(&deg[c], w[i]);
    atomicAdd(&cnt[c], 1);
  }
}

__global__ void k_dis(float* __restrict__ deg, int n) {
  int i = blockIdx.x * blockDim.x + threadIdx.x;
  if (i < n) deg[i] = rsqrtf(deg[i]);  // deg >= 1 always
}

// single-block in-place exclusive scan of cnt[0..n)
__global__ __launch_bounds__(1024) void k_scan(int* __restrict__ cnt, int n) {
  __shared__ int wsum[16];
  __shared__ int woff[17];
  const int lane = threadIdx.x & 63;
  const int wid  = threadIdx.x >> 6;
  int carry = 0;
  const int nchunk = (n + 1023) >> 10;
  for (int ch = 0; ch < nchunk; ++ch) {
    int i = (ch << 10) + threadIdx.x;
    int v = (i < n) ? cnt[i] : 0;
    int s = v;  // inclusive scan within wave
#pragma unroll
    for (int off = 1; off < 64; off <<= 1) {
      int t = __shfl_up(s, off);
      if (lane >= off) s += t;
    }
    if (lane == 63) wsum[wid] = s;
    __syncthreads();
    if (wid == 0 && lane < 16) {
      int u = wsum[lane];
#pragma unroll
      for (int off = 1; off < 16; off <<= 1) {
        int q = __shfl_up(u, off);
        if (lane >= off) u += q;
      }
      woff[lane + 1] = u;
      if (lane == 0) woff[0] = 0;
    }
    __syncthreads();
    int excl = s - v + woff[wid] + carry;
    if (i < n) cnt[i] = excl;
    carry += woff[16];
    __syncthreads();  // protect wsum/woff before next chunk
  }
}

// scatter edges into CSC; cnt holds exclusive starts, becomes end-pointers after
__global__ void k_scatter(int* __restrict__ cnt, const int* __restrict__ ei,
                          const float* __restrict__ w, const float* __restrict__ dis,
                          int* __restrict__ src, float* __restrict__ wn, int nE) {
  int i = blockIdx.x * blockDim.x + threadIdx.x;
  if (i < nE) {
    int r = ei[i];
    int c = ei[nE + i];
    int pos = atomicAdd(&cnt[c], 1);
    src[pos] = r;
    wn[pos]  = dis[r] * w[i] * dis[c];
  }
}

// ---------------- gather propagate (no atomics) ----------------
// f32 input, NS float4-slots per row
template<int NS>
__global__ void k_gather_f32(const float* __restrict__ X, const int* __restrict__ endp,
                             const int* __restrict__ src, const float* __restrict__ wn,
                             const float* __restrict__ dis, float* __restrict__ out, int n) {
  int tid = blockIdx.x * blockDim.x + threadIdx.x;
  int v = tid / NS;
  int s = tid - v * NS;
  if (v >= n) return;
  int beg = (v == 0) ? 0 : endp[v - 1];
  int end = endp[v];
  const float4* Xr = reinterpret_cast<const float4*>(X);
  float d = dis[v];
  float4 a = Xr[(size_t)v * NS + s];
  float sw = d * d;
  float4 acc = make_float4(a.x * sw, a.y * sw, a.z * sw, a.w * sw);
  for (int e = beg; e < end; ++e) {
    int r = src[e];
    float ww = wn[e];
    float4 xv = Xr[(size_t)r * NS + s];
    acc.x = fmaf(xv.x, ww, acc.x);
    acc.y = fmaf(xv.y, ww, acc.y);
    acc.z = fmaf(xv.z, ww, acc.z);
    acc.w = fmaf(xv.w, ww, acc.w);
  }
  reinterpret_cast<float4*>(out)[(size_t)v * NS + s] = acc;
}

// bf16 input (4 bf16 = 8B per slot), f32 output
template<int NS>
__global__ void k_gather_bf16(const unsigned short* __restrict__ X, const int* __restrict__ endp,
                              const int* __restrict__ src, const float* __restrict__ wn,
                              const float* __restrict__ dis, float* __restrict__ out, int n) {
  int tid = blockIdx.x * blockDim.x + threadIdx.x;
  int v = tid / NS;
  int s = tid - v * NS;
  if (v >= n) return;
  int beg = (v == 0) ? 0 : endp[v - 1];
  int end = endp[v];
  const uint2* Xr = reinterpret_cast<const uint2*>(X);
  float d = dis[v];
  float4 a = unpack_bf4(Xr[(size_t)v * NS + s]);
  float sw = d * d;
  float4 acc = make_float4(a.x * sw, a.y * sw, a.z * sw, a.w * sw);
  for (int e = beg; e < end; ++e) {
    int r = src[e];
    float ww = wn[e];
    float4 xv = unpack_bf4(Xr[(size_t)r * NS + s]);
    acc.x = fmaf(xv.x, ww, acc.x);
    acc.y = fmaf(xv.y, ww, acc.y);
    acc.z = fmaf(xv.z, ww, acc.z);
    acc.w = fmaf(xv.w, ww, acc.w);
  }
  reinterpret_cast<float4*>(out)[(size_t)v * NS + s] = acc;
}

// ---------------- SGEMM: C[M,Nn] = A[M,K] @ B[K,Nn] (+bias) ----------------
template<int BM, int BN, int BK, int TM, int TN, bool BF16OUT>
__global__ __launch_bounds__(256) void k_sgemm(const float* __restrict__ A,
    const float* __restrict__ B, const float* __restrict__ bias,
    void* __restrict__ Cv, int M, int Nn, int K) {
  __shared__ __align__(16) float As[BK][BM];  // A stored transposed
  __shared__ __align__(16) float Bs[BK][BN];
  const int tid = threadIdx.x;
  const int tx = tid % (BN / TN);
  const int ty = tid / (BN / TN);
  const int m0 = blockIdx.x * BM;
  const int n0 = blockIdx.y * BN;

  const int ar = tid >> 1;
  const int ak = (tid & 1) * 8;
  const int bk = tid >> 4;
  const int bc = (tid & 15) * 8;

  const bool a_ok = (m0 + ar) < M;
  const float* Ap = A + (size_t)(m0 + ar) * K + ak;
  const float* Bp = B + (size_t)bk * Nn + n0 + bc;

  float acc[TM][TN] = {};

  for (int k0 = 0; k0 < K; k0 += BK) {
    float av[8], bv[8];
    if (a_ok) {
      float4 a0 = *reinterpret_cast<const float4*>(Ap + k0);
      float4 a1 = *reinterpret_cast<const float4*>(Ap + k0 + 4);
      av[0] = a0.x; av[1] = a0.y; av[2] = a0.z; av[3] = a0.w;
      av[4] = a1.x; av[5] = a1.y; av[6] = a1.z; av[7] = a1.w;
    } else {
#pragma unroll
      for (int j = 0; j < 8; ++j) av[j] = 0.f;
    }
    if (n0 + bc + 8 <= Nn) {
      float4 b0 = *reinterpret_cast<const float4*>(Bp + (size_t)k0 * Nn);
      float4 b1 = *reinterpret_cast<const float4*>(Bp + (size_t)k0 * Nn + 4);
      bv[0] = b0.x; bv[1] = b0.y; bv[2] = b0.z; bv[3] = b0.w;
      bv[4] = b1.x; bv[5] = b1.y; bv[6] = b1.z; bv[7] = b1.w;
    } else {
#pragma unroll
      for (int j = 0; j < 8; ++j)
        bv[j] = (n0 + bc + j < Nn) ? Bp[(size_t)k0 * Nn + j] : 0.f;
    }
    __syncthreads();
#pragma unroll
    for (int j = 0; j < 8; ++j) As[ak + j][ar] = av[j];
    *reinterpret_cast<float4*>(&Bs[bk][bc])     = make_float4(bv[0], bv[1], bv[2], bv[3]);
    *reinterpret_cast<float4*>(&Bs[bk][bc + 4]) = make_float4(bv[4], bv[5], bv[6], bv[7]);
    __syncthreads();
#pragma unroll
    for (int kk = 0; kk < BK; ++kk) {
      float4 a0 = *reinterpret_cast<const float4*>(&As[kk][ty * TM]);
      float4 a1 = *reinterpret_cast<const float4*>(&As[kk][ty * TM + 4]);
      float4 b0 = *reinterpret_cast<const float4*>(&Bs[kk][tx * TN]);
      float4 b1 = *reinterpret_cast<const float4*>(&Bs[kk][tx * TN + 4]);
      float a[8] = {a0.x, a0.y, a0.z, a0.w, a1.x, a1.y, a1.z, a1.w};
      float b[8] = {b0.x, b0.y, b0.z, b0.w, b1.x, b1.y, b1.z, b1.w};
#pragma unroll
      for (int i = 0; i < TM; ++i)
#pragma unroll
        for (int j = 0; j < TN; ++j)
          acc[i][j] = fmaf(a[i], b[j], acc[i][j]);
    }
  }

#pragma unroll
  for (int i = 0; i < TM; ++i) {
    int m = m0 + ty * TM + i;
    if (m >= M) continue;
    if constexpr (BF16OUT) {
      unsigned short* Cp = reinterpret_cast<unsigned short*>(Cv) + (size_t)m * Nn;
#pragma unroll
      for (int j = 0; j < TN; j += 2) {  // Nn even, pairs never straddle
        int nn = n0 + tx * TN + j;
        if (nn < Nn) {
          unsigned pk = (unsigned)f2bf(acc[i][j]) | ((unsigned)f2bf(acc[i][j + 1]) << 16);
          *reinterpret_cast<unsigned*>(Cp + nn) = pk;
        }
      }
    } else {
      float* Cp = reinterpret_cast<float*>(Cv) + (size_t)m * Nn;
#pragma unroll
      for (int j = 0; j < TN; ++j) {
        int nn = n0 + tx * TN + j;
        if (nn < Nn) {
          float v = acc[i][j];
          if (bias) v += bias[nn];
          Cp[nn] = v;
        }
      }
    }
  }
}

// ---------------- BatchNorm ----------------
__global__ void k_bn_stats(const float* __restrict__ H, float* __restrict__ s1,
                           float* __restrict__ s2, int n, int C, int rpb) {
  int r0 = blockIdx.x * rpb;
  int r1 = r0 + rpb;
  if (r1 > n) r1 = n;
  for (int c = threadIdx.x; c < C; c += blockDim.x) {
    float a = 0.f, b = 0.f;
    for (int r = r0; r < r1; ++r) {
      float v = H[(size_t)r * C + c];
      a += v;
      b = fmaf(v, v, b);
    }
    atomAddF(&s1[c], a);
    atomAddF(&s2[c], b);
  }
}

__global__ void k_bn_finalize(const float* __restrict__ s1, const float* __restrict__ s2,
                              const float* __restrict__ g, const float* __restrict__ beta,
                              float* __restrict__ scale, float* __restrict__ shift,
                              int C, float invN) {
  int c = blockIdx.x * blockDim.x + threadIdx.x;
  if (c >= C) return;
  float mean = s1[c] * invN;
  float var = fmaxf(s2[c] * invN - mean * mean, 0.f);  // biased var
  float sc = g[c] * rsqrtf(var + kEps);
  scale[c] = sc;
  shift[c] = beta[c] - mean * sc;
}

template<int C>  // C power of 2
__global__ void k_bn_apply_relu(float* __restrict__ H, const float* __restrict__ scale,
                                const float* __restrict__ shift, int total4) {
  int i = blockIdx.x * blockDim.x + threadIdx.x;
  if (i >= total4) return;
  float4 v = reinterpret_cast<float4*>(H)[i];
  int c = (i * 4) & (C - 1);
  v.x = fmaxf(fmaf(v.x, scale[c],     shift[c]),     0.f);
  v.y = fmaxf(fmaf(v.y, scale[c + 1], shift[c + 1]), 0.f);
  v.z = fmaxf(fmaf(v.z, scale[c + 2], shift[c + 2]), 0.f);
  v.w = fmaxf(fmaf(v.w, scale[c + 3], shift[c + 3]), 0.f);
  reinterpret_cast<float4*>(H)[i] = v;
}

// ---------------- head: BN2-apply + relu + @Wl + bl + relu + log_softmax ----------------
__global__ __launch_bounds__(256) void k_head(const float* __restrict__ H,
    const float* __restrict__ scale, const float* __restrict__ shift,
    const float* __restrict__ Wl, const float* __restrict__ bl,
    float* __restrict__ out, int n) {
  __shared__ float sW[kH2 * kOut];
  __shared__ float sScale[kH2], sShift[kH2];
  for (int i = threadIdx.x; i < kH2 * kOut; i += blockDim.x) sW[i] = Wl[i];
  for (int i = threadIdx.x; i < kH2; i += blockDim.x) {
    sScale[i] = scale[i];
    sShift[i] = shift[i];
  }
  __syncthreads();
  float blv[kOut];
#pragma unroll
  for (int j = 0; j < kOut; ++j) blv[j] = bl[j];
  const int lane = threadIdx.x & 63;
  const int wid = (blockIdx.x * blockDim.x + threadIdx.x) >> 6;
  const int nw  = (gridDim.x * blockDim.x) >> 6;
  for (int node = wid; node < n; node += nw) {
    const float* hrow = H + (size_t)node * kH2;
    float acc[kOut] = {};
    for (int k = lane; k < kH2; k += 64) {
      float v = fmaxf(fmaf(hrow[k], sScale[k], sShift[k]), 0.f);
      const float* wr = sW + k * kOut;
#pragma unroll
      for (int j = 0; j < kOut; ++j) acc[j] = fmaf(v, wr[j], acc[j]);
    }
#pragma unroll
    for (int j = 0; j < kOut; ++j) {
      float v = acc[j];
      for (int off = 32; off > 0; off >>= 1) v += __shfl_down(v, off);
      acc[j] = v;  // valid on lane 0
    }
    if (lane == 0) {
      float vv[kOut], m = -1e30f;
#pragma unroll
      for (int j = 0; j < kOut; ++j) {
        vv[j] = fmaxf(acc[j] + blv[j], 0.f);
        m = fmaxf(m, vv[j]);
      }
      float s = 0.f;
#pragma unroll
      for (int j = 0; j < kOut; ++j) s += expf(vv[j] - m);
      float lse = m + logf(s);
      float* o = out + (size_t)node * kOut;
#pragma unroll
      for (int j = 0; j < kOut; ++j) o[j] = vv[j] - lse;
    }
  }
}

}  // namespace

extern "C" void kernel_launch(void* const* d_in, const int* in_sizes, int n_in,
                              void* d_out, int out_size, void* d_ws, size_t ws_size,
                              hipStream_t stream) {
  const float* x   = (const float*)d_in[0];
  const int*   ei  = (const int*)d_in[1];
  const float* ew  = (const float*)d_in[2];
  const float* W1  = (const float*)d_in[3];
  const float* b1  = (const float*)d_in[4];
  const float* g1  = (const float*)d_in[5];
  const float* be1 = (const float*)d_in[6];
  const float* W2  = (const float*)d_in[7];
  // d_in[8] = b2: cancelled exactly by BN2 mean-subtraction — skipped
  const float* g2  = (const float*)d_in[9];
  const float* be2 = (const float*)d_in[10];
  const float* Wl  = (const float*)d_in[11];
  const float* bl  = (const float*)d_in[12];
  float* out = (float*)d_out;
  float* ws  = (float*)d_ws;

  const int n = in_sizes[0] / kIn;  // 50000
  const int e = in_sizes[1] / 2;    // 800000

  // workspace layout (float units), total ~139 MB:
  //   dis    [0, 50048)
  //   cnt    [50048, 100096)           int; exclusive starts -> end-pointers
  //   src    [100096, 900096)          int
  //   wn     [900096, 1700096)
  //   st     [1700096, 1704192)        BN stats/scale/shift
  //   t2slot [1704192, 9204192)        agg1 (N*128 f32 = 6.4M) then t2 (N*300 bf16 = 7.5M)
  //   h1slot [9204192, 34804192)       h1 (N*512 f32 = 25.6M), agg2 (N*300 f32 = 15M) aliases
  float* dis = ws;
  int*   cnt = (int*)(ws + 50048);
  int*   src = (int*)(ws + 100096);
  float* wn  = ws + 900096;
  float* st  = ws + 1700096;
  float* s1a = st,        *s2a = st + 512,  *sc1 = st + 1024, *sh1 = st + 1536;
  float* s1b = st + 2048, *s2b = st + 2560, *sc2 = st + 3072, *sh2 = st + 3584;
  float* agg1 = ws + 1704192;
  unsigned short* t2 = (unsigned short*)agg1;
  float* h1   = ws + 9204192;
  float* agg2 = h1;

  constexpr int TPB = 256;

  // ---- build CSC + normalization ----
  k_init<<<(n + TPB - 1) / TPB, TPB, 0, stream>>>(dis, cnt, n);
  k_deg_cnt<<<(e + TPB - 1) / TPB, TPB, 0, stream>>>(dis, cnt, ei, ew, e);
  k_dis<<<(n + TPB - 1) / TPB, TPB, 0, stream>>>(dis, n);
  k_scan<<<1, 1024, 0, stream>>>(cnt, n);
  k_scatter<<<(e + TPB - 1) / TPB, TPB, 0, stream>>>(cnt, ei, ew, dis, src, wn, e);
  hipMemsetAsync(st, 0, 4096 * sizeof(float), stream);

  // ---- layer 1: agg1 = A(x); h1 = agg1@W1 + b1; BN+relu ----
  {
    long long tot = (long long)n * (kIn / 4);
    k_gather_f32<kIn / 4><<<(int)((tot + TPB - 1) / TPB), TPB, 0, stream>>>(
        x, cnt, src, wn, dis, agg1, n);
  }
  {
    dim3 g((n + 127) / 128, (kH1 + 127) / 128);
    k_sgemm<128, 128, 16, 8, 8, false><<<g, 256, 0, stream>>>(agg1, W1, b1, h1, n, kH1, kIn);
  }
  k_bn_stats<<<512, 256, 0, stream>>>(h1, s1a, s2a, n, kH1, (n + 511) / 512);
  k_bn_finalize<<<(kH1 + 255) / 256, 256, 0, stream>>>(s1a, s2a, g1, be1, sc1, sh1, kH1, 1.0f / n);
  k_bn_apply_relu<kH1><<<((n * (kH1 / 4)) + TPB - 1) / TPB, TPB, 0, stream>>>(h1, sc1, sh1, n * (kH1 / 4));

  // ---- layer 2: t2 = bf16(h1@W2); agg2 = A(t2); BN stats ----
  {
    dim3 g((n + 127) / 128, (kH2 + 127) / 128);
    k_sgemm<128, 128, 16, 8, 8, true><<<g, 256, 0, stream>>>(h1, W2, nullptr, t2, n, kH2, kH1);
  }
  {
    long long tot = (long long)n * (kH2 / 4);
    k_gather_bf16<kH2 / 4><<<(int)((tot + TPB - 1) / TPB), TPB, 0, stream>>>(
        t2, cnt, src, wn, dis, agg2, n);
  }
  k_bn_stats<<<512, 256, 0, stream>>>(agg2, s1b, s2b, n, kH2, (n + 511) / 512);
  k_bn_finalize<<<(kH2 + 255) / 256, 256, 0, stream>>>(s1b, s2b, g2, be2, sc2, sh2, kH2, 1.0f / n);

  // ---- head: BN2-apply + relu + @Wl + bl + relu + log_softmax ----
  k_head<<<1024, 256, 0, stream>>>(agg2, sc2, sh2, Wl, bl, out, n);
}

// Round 3
// 648.821 us; speedup vs baseline: 8.7459x; 1.4191x over previous
//
#include <hip/hip_runtime.h>
#include <math.h>

namespace {

constexpr int kIn  = 128;
constexpr int kH1  = 512;
constexpr int kH2  = 300;
constexpr int kOut = 10;
constexpr float kEps = 1e-5f;

typedef __attribute__((ext_vector_type(8))) short bf16x8;
typedef __attribute__((ext_vector_type(4))) float f32x4;

__device__ __forceinline__ void atomAddF(float* p, float v) {
  unsafeAtomicAdd(p, v);
}

__device__ __forceinline__ unsigned short f2bf(float f) {  // RNE f32->bf16
  unsigned u = __builtin_bit_cast(unsigned, f);
  unsigned r = u + 0x7fffu + ((u >> 16) & 1u);
  return (unsigned short)(r >> 16);
}

__device__ __forceinline__ float bf2f(unsigned short h) {
  return __builtin_bit_cast(float, (unsigned)h << 16);
}

__device__ __forceinline__ float4 unpack_bf4(uint2 q) {
  float4 r;
  r.x = __builtin_bit_cast(float, (q.x & 0xffffu) << 16);
  r.y = __builtin_bit_cast(float, q.x & 0xffff0000u);
  r.z = __builtin_bit_cast(float, (q.y & 0xffffu) << 16);
  r.w = __builtin_bit_cast(float, q.y & 0xffff0000u);
  return r;
}

// ---------------- degree / counting ----------------
__global__ void k_init(float* __restrict__ deg, int* __restrict__ cnt, int n) {
  int i = blockIdx.x * blockDim.x + threadIdx.x;
  if (i < n) { deg[i] = 1.0f; cnt[i] = 0; }
}

__global__ void k_deg_cnt(float* __restrict__ deg, int* __restrict__ cnt,
                          const int* __restrict__ ei, const float* __restrict__ w, int nE) {
  int i = blockIdx.x * blockDim.x + threadIdx.x;
  if (i < nE) {
    int c = ei[nE + i];
    atomAddF(&deg[c], w[i]);
    atomicAdd(&cnt[c], 1);
  }
}

__global__ void k_dis(float* __restrict__ deg, int n) {
  int i = blockIdx.x * blockDim.x + threadIdx.x;
  if (i < n) deg[i] = rsqrtf(deg[i]);
}

// single-block in-place exclusive scan
__global__ __launch_bounds__(1024) void k_scan(int* __restrict__ cnt, int n) {
  __shared__ int wsum[16];
  __shared__ int woff[17];
  const int lane = threadIdx.x & 63;
  const int wid  = threadIdx.x >> 6;
  int carry = 0;
  const int nchunk = (n + 1023) >> 10;
  for (int ch = 0; ch < nchunk; ++ch) {
    int i = (ch << 10) + threadIdx.x;
    int v = (i < n) ? cnt[i] : 0;
    int s = v;
#pragma unroll
    for (int off = 1; off < 64; off <<= 1) {
      int t = __shfl_up(s, off);
      if (lane >= off) s += t;
    }
    if (lane == 63) wsum[wid] = s;
    __syncthreads();
    if (wid == 0 && lane < 16) {
      int u = wsum[lane];
#pragma unroll
      for (int off = 1; off < 16; off <<= 1) {
        int q = __shfl_up(u, off);
        if (lane >= off) u += q;
      }
      woff[lane + 1] = u;
      if (lane == 0) woff[0] = 0;
    }
    __syncthreads();
    int excl = s - v + woff[wid] + carry;
    if (i < n) cnt[i] = excl;
    carry += woff[16];
    __syncthreads();
  }
}

__global__ void k_scatter(int* __restrict__ cnt, const int* __restrict__ ei,
                          const float* __restrict__ w, const float* __restrict__ dis,
                          int* __restrict__ src, float* __restrict__ wn, int nE) {
  int i = blockIdx.x * blockDim.x + threadIdx.x;
  if (i < nE) {
    int r = ei[i];
    int c = ei[nE + i];
    int pos = atomicAdd(&cnt[c], 1);
    src[pos] = r;
    wn[pos]  = dis[r] * w[i] * dis[c];
  }
}

// ---------------- weight transpose + bf16 convert: W[K][N] -> WT[N][K] bf16 ----------------
__global__ void k_wt(const float* __restrict__ W, unsigned short* __restrict__ WT, int K, int N) {
  int idx = blockIdx.x * blockDim.x + threadIdx.x;
  if (idx >= K * N) return;
  int n = idx / K, k = idx - n * K;
  WT[idx] = f2bf(W[(size_t)k * N + n]);
}

// ---------------- gather propagate (no atomics) ----------------
// f32 input -> bf16 output (for GEMM1 A operand)
template<int NS>
__global__ void k_gather_x(const float* __restrict__ X, const int* __restrict__ endp,
                           const int* __restrict__ src, const float* __restrict__ wn,
                           const float* __restrict__ dis, unsigned short* __restrict__ out, int n) {
  int tid = blockIdx.x * blockDim.x + threadIdx.x;
  int v = tid / NS;
  int s = tid - v * NS;
  if (v >= n) return;
  int beg = (v == 0) ? 0 : endp[v - 1];
  int end = endp[v];
  const float4* Xr = reinterpret_cast<const float4*>(X);
  float d = dis[v];
  float4 a = Xr[(size_t)v * NS + s];
  float sw = d * d;
  float4 acc = make_float4(a.x * sw, a.y * sw, a.z * sw, a.w * sw);
  for (int e = beg; e < end; ++e) {
    int r = src[e];
    float ww = wn[e];
    float4 xv = Xr[(size_t)r * NS + s];
    acc.x = fmaf(xv.x, ww, acc.x);
    acc.y = fmaf(xv.y, ww, acc.y);
    acc.z = fmaf(xv.z, ww, acc.z);
    acc.w = fmaf(xv.w, ww, acc.w);
  }
  uint2 pk;
  pk.x = (unsigned)f2bf(acc.x) | ((unsigned)f2bf(acc.y) << 16);
  pk.y = (unsigned)f2bf(acc.z) | ((unsigned)f2bf(acc.w) << 16);
  reinterpret_cast<uint2*>(out)[(size_t)v * NS + s] = pk;
}

// bf16 input -> f32 output (layer-2 aggregation)
template<int NS>
__global__ void k_gather_bf16(const unsigned short* __restrict__ X, const int* __restrict__ endp,
                              const int* __restrict__ src, const float* __restrict__ wn,
                              const float* __restrict__ dis, float* __restrict__ out, int n) {
  int tid = blockIdx.x * blockDim.x + threadIdx.x;
  int v = tid / NS;
  int s = tid - v * NS;
  if (v >= n) return;
  int beg = (v == 0) ? 0 : endp[v - 1];
  int end = endp[v];
  const uint2* Xr = reinterpret_cast<const uint2*>(X);
  float d = dis[v];
  float4 a = unpack_bf4(Xr[(size_t)v * NS + s]);
  float sw = d * d;
  float4 acc = make_float4(a.x * sw, a.y * sw, a.z * sw, a.w * sw);
  for (int e = beg; e < end; ++e) {
    int r = src[e];
    float ww = wn[e];
    float4 xv = unpack_bf4(Xr[(size_t)r * NS + s]);
    acc.x = fmaf(xv.x, ww, acc.x);
    acc.y = fmaf(xv.y, ww, acc.y);
    acc.z = fmaf(xv.z, ww, acc.z);
    acc.w = fmaf(xv.w, ww, acc.w);
  }
  reinterpret_cast<float4*>(out)[(size_t)v * NS + s] = acc;
}

// ---------------- bf16 MFMA GEMM: C[M,Nlog] = A[M,K](bf16) @ BT[Nlog,K](bf16)^T ----------------
// 128x128 tile, 4 waves 2x2, each wave 64x64 = 4x4 frags of 16x16x32. BK=32.
// LDS granule layout (k8, row): idx = k8*128 + row, 16B per granule -> conflict-free b128 r/w.
template<bool BF16OUT>
__global__ __launch_bounds__(256) void k_gemm(const unsigned short* __restrict__ A,
                                              const unsigned short* __restrict__ BT,
                                              void* __restrict__ C, int M, int Nlog, int K) {
  constexpr int BM = 128, BN = 128, BK = 32;
  __shared__ unsigned short lA[(BK / 8) * BM * 8];
  __shared__ unsigned short lB[(BK / 8) * BN * 8];
  const int tid  = threadIdx.x;
  const int lane = tid & 63;
  const int wid  = tid >> 6;
  const int wr   = wid >> 1;   // wave row 0..1
  const int wc   = wid & 1;    // wave col 0..1
  const int m0 = blockIdx.x * BM;
  const int n0 = blockIdx.y * BN;

  const int sm  = tid >> 2;    // staging row 0..63 (and +64)
  const int sk8 = tid & 3;     // staging k8
  const int fr = lane & 15, fq = lane >> 4;

  f32x4 acc[4][4] = {};

  for (int k0 = 0; k0 < K; k0 += BK) {
    uint4 a0, a1, b0, b1;
    {
      const uint4 z = make_uint4(0, 0, 0, 0);
      int r0 = m0 + sm, r1 = m0 + sm + 64;
      a0 = (r0 < M) ? *reinterpret_cast<const uint4*>(A + (size_t)r0 * K + k0 + sk8 * 8) : z;
      a1 = (r1 < M) ? *reinterpret_cast<const uint4*>(A + (size_t)r1 * K + k0 + sk8 * 8) : z;
      int c0 = n0 + sm, c1 = n0 + sm + 64;
      b0 = (c0 < Nlog) ? *reinterpret_cast<const uint4*>(BT + (size_t)c0 * K + k0 + sk8 * 8) : z;
      b1 = (c1 < Nlog) ? *reinterpret_cast<const uint4*>(BT + (size_t)c1 * K + k0 + sk8 * 8) : z;
    }
    __syncthreads();  // previous iteration's frag reads done
    *reinterpret_cast<uint4*>(lA + (sk8 * BM + sm) * 8)      = a0;
    *reinterpret_cast<uint4*>(lA + (sk8 * BM + sm + 64) * 8) = a1;
    *reinterpret_cast<uint4*>(lB + (sk8 * BN + sm) * 8)      = b0;
    *reinterpret_cast<uint4*>(lB + (sk8 * BN + sm + 64) * 8) = b1;
    __syncthreads();

    bf16x8 af[4], bfr[4];
#pragma unroll
    for (int m = 0; m < 4; ++m)
      af[m] = *reinterpret_cast<const bf16x8*>(lA + (fq * BM + wr * 64 + m * 16 + fr) * 8);
#pragma unroll
    for (int nn = 0; nn < 4; ++nn)
      bfr[nn] = *reinterpret_cast<const bf16x8*>(lB + (fq * BN + wc * 64 + nn * 16 + fr) * 8);
#pragma unroll
    for (int m = 0; m < 4; ++m)
#pragma unroll
      for (int nn = 0; nn < 4; ++nn)
        acc[m][nn] = __builtin_amdgcn_mfma_f32_16x16x32_bf16(af[m], bfr[nn], acc[m][nn], 0, 0, 0);
  }

#pragma unroll
  for (int m = 0; m < 4; ++m) {
#pragma unroll
    for (int r = 0; r < 4; ++r) {
      int row = m0 + wr * 64 + m * 16 + fq * 4 + r;
      if (row >= M) continue;
#pragma unroll
      for (int nn = 0; nn < 4; ++nn) {
        int col = n0 + wc * 64 + nn * 16 + fr;
        if (col < Nlog) {
          float v = acc[m][nn][r];
          if constexpr (BF16OUT)
            reinterpret_cast<unsigned short*>(C)[(size_t)row * Nlog + col] = f2bf(v);
          else
            reinterpret_cast<float*>(C)[(size_t)row * Nlog + col] = v;
        }
      }
    }
  }
}

// ---------------- BatchNorm ----------------
__global__ void k_bn_stats_bf16(const unsigned short* __restrict__ H, float* __restrict__ s1,
                                float* __restrict__ s2, int n, int C, int rpb) {
  int r0 = blockIdx.x * rpb;
  int r1 = r0 + rpb;
  if (r1 > n) r1 = n;
  for (int c = threadIdx.x; c < C; c += blockDim.x) {
    float a = 0.f, b = 0.f;
    for (int r = r0; r < r1; ++r) {
      float v = bf2f(H[(size_t)r * C + c]);
      a += v;
      b = fmaf(v, v, b);
    }
    atomAddF(&s1[c], a);
    atomAddF(&s2[c], b);
  }
}

__global__ void k_bn_stats(const float* __restrict__ H, float* __restrict__ s1,
                           float* __restrict__ s2, int n, int C, int rpb) {
  int r0 = blockIdx.x * rpb;
  int r1 = r0 + rpb;
  if (r1 > n) r1 = n;
  for (int c = threadIdx.x; c < C; c += blockDim.x) {
    float a = 0.f, b = 0.f;
    for (int r = r0; r < r1; ++r) {
      float v = H[(size_t)r * C + c];
      a += v;
      b = fmaf(v, v, b);
    }
    atomAddF(&s1[c], a);
    atomAddF(&s2[c], b);
  }
}

__global__ void k_bn_finalize(const float* __restrict__ s1, const float* __restrict__ s2,
                              const float* __restrict__ g, const float* __restrict__ beta,
                              float* __restrict__ scale, float* __restrict__ shift,
                              int C, float invN) {
  int c = blockIdx.x * blockDim.x + threadIdx.x;
  if (c >= C) return;
  float mean = s1[c] * invN;
  float var = fmaxf(s2[c] * invN - mean * mean, 0.f);
  float sc = g[c] * rsqrtf(var + kEps);
  scale[c] = sc;
  shift[c] = beta[c] - mean * sc;
}

// in-place BN+ReLU on bf16 buffer, 8 elems per thread. C power of 2.
template<int C>
__global__ void k_bn_apply_relu_bf16(unsigned short* __restrict__ H,
                                     const float* __restrict__ scale,
                                     const float* __restrict__ shift, int total8) {
  int i = blockIdx.x * blockDim.x + threadIdx.x;
  if (i >= total8) return;
  uint4 q = reinterpret_cast<uint4*>(H)[i];
  int c = (i * 8) & (C - 1);
  unsigned w[4] = {q.x, q.y, q.z, q.w};
  unsigned o[4];
#pragma unroll
  for (int j = 0; j < 4; ++j) {
    float lo = __builtin_bit_cast(float, (w[j] & 0xffffu) << 16);
    float hi = __builtin_bit_cast(float, w[j] & 0xffff0000u);
    int cl = c + j * 2;
    lo = fmaxf(fmaf(lo, scale[cl],     shift[cl]),     0.f);
    hi = fmaxf(fmaf(hi, scale[cl + 1], shift[cl + 1]), 0.f);
    o[j] = (unsigned)f2bf(lo) | ((unsigned)f2bf(hi) << 16);
  }
  reinterpret_cast<uint4*>(H)[i] = make_uint4(o[0], o[1], o[2], o[3]);
}

// ---------------- head ----------------
__global__ __launch_bounds__(256) void k_head(const float* __restrict__ H,
    const float* __restrict__ scale, const float* __restrict__ shift,
    const float* __restrict__ Wl, const float* __restrict__ bl,
    float* __restrict__ out, int n) {
  __shared__ float sW[kH2 * kOut];
  __shared__ float sScale[kH2], sShift[kH2];
  for (int i = threadIdx.x; i < kH2 * kOut; i += blockDim.x) sW[i] = Wl[i];
  for (int i = threadIdx.x; i < kH2; i += blockDim.x) {
    sScale[i] = scale[i];
    sShift[i] = shift[i];
  }
  __syncthreads();
  float blv[kOut];
#pragma unroll
  for (int j = 0; j < kOut; ++j) blv[j] = bl[j];
  const int lane = threadIdx.x & 63;
  const int wid = (blockIdx.x * blockDim.x + threadIdx.x) >> 6;
  const int nw  = (gridDim.x * blockDim.x) >> 6;
  for (int node = wid; node < n; node += nw) {
    const float* hrow = H + (size_t)node * kH2;
    float acc[kOut] = {};
    for (int k = lane; k < kH2; k += 64) {
      float v = fmaxf(fmaf(hrow[k], sScale[k], sShift[k]), 0.f);
      const float* wr = sW + k * kOut;
#pragma unroll
      for (int j = 0; j < kOut; ++j) acc[j] = fmaf(v, wr[j], acc[j]);
    }
#pragma unroll
    for (int j = 0; j < kOut; ++j) {
      float v = acc[j];
      for (int off = 32; off > 0; off >>= 1) v += __shfl_down(v, off);
      acc[j] = v;
    }
    if (lane == 0) {
      float vv[kOut], m = -1e30f;
#pragma unroll
      for (int j = 0; j < kOut; ++j) {
        vv[j] = fmaxf(acc[j] + blv[j], 0.f);
        m = fmaxf(m, vv[j]);
      }
      float s = 0.f;
#pragma unroll
      for (int j = 0; j < kOut; ++j) s += expf(vv[j] - m);
      float lse = m + logf(s);
      float* o = out + (size_t)node * kOut;
#pragma unroll
      for (int j = 0; j < kOut; ++j) o[j] = vv[j] - lse;
    }
  }
}

}  // namespace

extern "C" void kernel_launch(void* const* d_in, const int* in_sizes, int n_in,
                              void* d_out, int out_size, void* d_ws, size_t ws_size,
                              hipStream_t stream) {
  const float* x   = (const float*)d_in[0];
  const int*   ei  = (const int*)d_in[1];
  const float* ew  = (const float*)d_in[2];
  const float* W1  = (const float*)d_in[3];
  // d_in[4] = b1: constant per column before BN1 -> cancelled by mean subtraction
  const float* g1  = (const float*)d_in[5];
  const float* be1 = (const float*)d_in[6];
  const float* W2  = (const float*)d_in[7];
  // d_in[8] = b2: cancelled by BN2
  const float* g2  = (const float*)d_in[9];
  const float* be2 = (const float*)d_in[10];
  const float* Wl  = (const float*)d_in[11];
  const float* bl  = (const float*)d_in[12];
  float* out = (float*)d_out;
  float* ws  = (float*)d_ws;

  const int n = in_sizes[0] / kIn;  // 50000
  const int e = in_sizes[1] / 2;    // 800000

  // workspace (float units), total ~148.5 MB:
  float* dis = ws;                                   // 50048
  int*   cnt = (int*)(ws + 50048);                   // 50048
  int*   src = (int*)(ws + 100096);                  // 800000
  float* wn  = ws + 900096;                          // 800000
  float* st  = ws + 1700096;                         // 4096
  float* s1a = st,        *s2a = st + 512,  *sc1 = st + 1024, *sh1 = st + 1536;
  float* s1b = st + 2048, *s2b = st + 2560, *sc2 = st + 3072, *sh2 = st + 3584;
  unsigned short* W1T = (unsigned short*)(ws + 1704192);  // 512x128 bf16 = 32768 fl
  unsigned short* W2T = (unsigned short*)(ws + 1736960);  // 300x512 bf16 = 76800 fl
  // slotA: agg1 bf16 (N*128 = 3.2M fl) then t2 bf16 (N*300 = 7.5M fl)
  unsigned short* agg1 = (unsigned short*)(ws + 1813760);
  unsigned short* t2   = agg1;
  unsigned short* h1bf = (unsigned short*)(ws + 9313760);  // N*512 bf16 = 12.8M fl
  float* agg2 = ws + 22113760;                             // N*300 f32 = 15M fl

  constexpr int TPB = 256;

  // ---- CSC build + normalization ----
  k_init<<<(n + TPB - 1) / TPB, TPB, 0, stream>>>(dis, cnt, n);
  k_deg_cnt<<<(e + TPB - 1) / TPB, TPB, 0, stream>>>(dis, cnt, ei, ew, e);
  k_dis<<<(n + TPB - 1) / TPB, TPB, 0, stream>>>(dis, n);
  k_scan<<<1, 1024, 0, stream>>>(cnt, n);
  k_scatter<<<(e + TPB - 1) / TPB, TPB, 0, stream>>>(cnt, ei, ew, dis, src, wn, e);
  hipMemsetAsync(st, 0, 4096 * sizeof(float), stream);

  // ---- weight prep ----
  k_wt<<<(kIn * kH1 + TPB - 1) / TPB, TPB, 0, stream>>>(W1, W1T, kIn, kH1);
  k_wt<<<(kH1 * kH2 + TPB - 1) / TPB, TPB, 0, stream>>>(W2, W2T, kH1, kH2);

  // ---- layer 1: agg1 = A(x) [bf16]; h1bf = bf16(agg1@W1); BN1 stats; in-place BN+ReLU ----
  {
    long long tot = (long long)n * (kIn / 4);
    k_gather_x<kIn / 4><<<(int)((tot + TPB - 1) / TPB), TPB, 0, stream>>>(
        x, cnt, src, wn, dis, agg1, n);
  }
  {
    dim3 g((n + 127) / 128, (kH1 + 127) / 128);
    k_gemm<true><<<g, 256, 0, stream>>>(agg1, W1T, h1bf, n, kH1, kIn);
  }
  k_bn_stats_bf16<<<512, 256, 0, stream>>>(h1bf, s1a, s2a, n, kH1, (n + 511) / 512);
  k_bn_finalize<<<(kH1 + 255) / 256, 256, 0, stream>>>(s1a, s2a, g1, be1, sc1, sh1, kH1, 1.0f / n);
  k_bn_apply_relu_bf16<kH1><<<((n * (kH1 / 8)) + TPB - 1) / TPB, TPB, 0, stream>>>(
      h1bf, sc1, sh1, n * (kH1 / 8));

  // ---- layer 2: t2 = bf16(h1bf@W2); agg2 = A(t2) [f32]; BN2 stats ----
  {
    dim3 g((n + 127) / 128, (kH2 + 127) / 128);
    k_gemm<true><<<g, 256, 0, stream>>>(h1bf, W2T, t2, n, kH2, kH1);
  }
  {
    long long tot = (long long)n * (kH2 / 4);
    k_gather_bf16<kH2 / 4><<<(int)((tot + TPB - 1) / TPB), TPB, 0, stream>>>(
        t2, cnt, src, wn, dis, agg2, n);
  }
  k_bn_stats<<<512, 256, 0, stream>>>(agg2, s1b, s2b, n, kH2, (n + 511) / 512);
  k_bn_finalize<<<(kH2 + 255) / 256, 256, 0, stream>>>(s1b, s2b, g2, be2, sc2, sh2, kH2, 1.0f / n);

  // ---- head ----
  k_head<<<1024, 256, 0, stream>>>(agg2, sc2, sh2, Wl, bl, out, n);
}

// Round 4
// 562.216 us; speedup vs baseline: 10.0932x; 1.1540x over previous
//
#include <hip/hip_runtime.h>
#include <math.h>

namespace {

constexpr int kIn  = 128;
constexpr int kH1  = 512;
constexpr int kH2  = 300;
constexpr int kH2p = 304;   // padded to 16B-granule multiple (8 bf16)
constexpr int kOut = 10;
constexpr float kEps = 1e-5f;

typedef __attribute__((ext_vector_type(8))) short bf16x8;
typedef __attribute__((ext_vector_type(4))) float f32x4;

__device__ __forceinline__ void atomAddF(float* p, float v) {
  unsafeAtomicAdd(p, v);
}

__device__ __forceinline__ unsigned short f2bf(float f) {  // RNE f32->bf16
  unsigned u = __builtin_bit_cast(unsigned, f);
  unsigned r = u + 0x7fffu + ((u >> 16) & 1u);
  return (unsigned short)(r >> 16);
}

__device__ __forceinline__ float bf2f(unsigned short h) {
  return __builtin_bit_cast(float, (unsigned)h << 16);
}

__device__ __forceinline__ float blo(unsigned u) {
  return __builtin_bit_cast(float, u << 16);
}
__device__ __forceinline__ float bhi(unsigned u) {
  return __builtin_bit_cast(float, u & 0xffff0000u);
}

__device__ __forceinline__ void fma8(const uint4& q, float w, float* acc) {
  acc[0] = fmaf(blo(q.x), w, acc[0]);
  acc[1] = fmaf(bhi(q.x), w, acc[1]);
  acc[2] = fmaf(blo(q.y), w, acc[2]);
  acc[3] = fmaf(bhi(q.y), w, acc[3]);
  acc[4] = fmaf(blo(q.z), w, acc[4]);
  acc[5] = fmaf(bhi(q.z), w, acc[5]);
  acc[6] = fmaf(blo(q.w), w, acc[6]);
  acc[7] = fmaf(bhi(q.w), w, acc[7]);
}

// ---------------- degree / counting ----------------
__global__ void k_init(float* __restrict__ deg, int* __restrict__ cnt, int n) {
  int i = blockIdx.x * blockDim.x + threadIdx.x;
  if (i < n) { deg[i] = 1.0f; cnt[i] = 0; }
}

__global__ void k_deg_cnt(float* __restrict__ deg, int* __restrict__ cnt,
                          const int* __restrict__ ei, const float* __restrict__ w, int nE) {
  int i = blockIdx.x * blockDim.x + threadIdx.x;
  if (i < nE) {
    int c = ei[nE + i];
    atomAddF(&deg[c], w[i]);
    atomicAdd(&cnt[c], 1);
  }
}

__global__ void k_dis(float* __restrict__ deg, int n) {
  int i = blockIdx.x * blockDim.x + threadIdx.x;
  if (i < n) deg[i] = rsqrtf(deg[i]);
}

// single-block in-place exclusive scan
__global__ __launch_bounds__(1024) void k_scan(int* __restrict__ cnt, int n) {
  __shared__ int wsum[16];
  __shared__ int woff[17];
  const int lane = threadIdx.x & 63;
  const int wid  = threadIdx.x >> 6;
  int carry = 0;
  const int nchunk = (n + 1023) >> 10;
  for (int ch = 0; ch < nchunk; ++ch) {
    int i = (ch << 10) + threadIdx.x;
    int v = (i < n) ? cnt[i] : 0;
    int s = v;
#pragma unroll
    for (int off = 1; off < 64; off <<= 1) {
      int t = __shfl_up(s, off);
      if (lane >= off) s += t;
    }
    if (lane == 63) wsum[wid] = s;
    __syncthreads();
    if (wid == 0 && lane < 16) {
      int u = wsum[lane];
#pragma unroll
      for (int off = 1; off < 16; off <<= 1) {
        int q = __shfl_up(u, off);
        if (lane >= off) u += q;
      }
      woff[lane + 1] = u;
      if (lane == 0) woff[0] = 0;
    }
    __syncthreads();
    int excl = s - v + woff[wid] + carry;
    if (i < n) cnt[i] = excl;
    carry += woff[16];
    __syncthreads();
  }
}

// scatter edges into CSC as interleaved (src, weight) pairs
__global__ void k_scatter(int* __restrict__ cnt, const int* __restrict__ ei,
                          const float* __restrict__ w, const float* __restrict__ dis,
                          uint2* __restrict__ pr, int nE) {
  int i = blockIdx.x * blockDim.x + threadIdx.x;
  if (i < nE) {
    int r = ei[i];
    int c = ei[nE + i];
    int pos = atomicAdd(&cnt[c], 1);
    float ww = dis[r] * w[i] * dis[c];
    pr[pos] = make_uint2((unsigned)r, __builtin_bit_cast(unsigned, ww));
  }
}

// ---------------- x f32 -> bf16 ----------------
__global__ void k_xbf(const float* __restrict__ X, unsigned short* __restrict__ O, int total4) {
  int i = blockIdx.x * blockDim.x + threadIdx.x;
  if (i >= total4) return;
  float4 v = reinterpret_cast<const float4*>(X)[i];
  uint2 pk;
  pk.x = (unsigned)f2bf(v.x) | ((unsigned)f2bf(v.y) << 16);
  pk.y = (unsigned)f2bf(v.z) | ((unsigned)f2bf(v.w) << 16);
  reinterpret_cast<uint2*>(O)[i] = pk;
}

// ---------------- weight transpose + bf16 (+row pad with zeros) ----------------
// W[K][Nsrc] -> WT[Npad][K] bf16, rows >= Nsrc are zero
__global__ void k_wt(const float* __restrict__ W, unsigned short* __restrict__ WT,
                     int K, int Nsrc, int Npad) {
  int idx = blockIdx.x * blockDim.x + threadIdx.x;
  if (idx >= K * Npad) return;
  int n = idx / K, k = idx - n * K;
  WT[idx] = (n < Nsrc) ? f2bf(W[(size_t)k * Nsrc + n]) : (unsigned short)0;
}

// ---------------- gather propagate: bf16 in, bf16 out, 16B granules, 4x unrolled ----------------
template<int NSQ>  // uint4 granules per row
__global__ void k_gather(const unsigned short* __restrict__ X, const int* __restrict__ endp,
                         const uint2* __restrict__ pr, const float* __restrict__ dis,
                         unsigned short* __restrict__ out, int n) {
  int tid = blockIdx.x * blockDim.x + threadIdx.x;
  int v = tid / NSQ;
  int s = tid - v * NSQ;
  if (v >= n) return;
  int beg = (v == 0) ? 0 : endp[v - 1];
  int end = endp[v];
  const uint4* Xr = reinterpret_cast<const uint4*>(X);
  float d = dis[v];
  float sw = d * d;
  float acc[8];
  {
    uint4 q = Xr[(size_t)v * NSQ + s];
    acc[0] = blo(q.x) * sw; acc[1] = bhi(q.x) * sw;
    acc[2] = blo(q.y) * sw; acc[3] = bhi(q.y) * sw;
    acc[4] = blo(q.z) * sw; acc[5] = bhi(q.z) * sw;
    acc[6] = blo(q.w) * sw; acc[7] = bhi(q.w) * sw;
  }
  int e = beg;
  for (; e + 4 <= end; e += 4) {
    uint2 p0 = pr[e], p1 = pr[e + 1], p2 = pr[e + 2], p3 = pr[e + 3];
    uint4 q0 = Xr[(size_t)p0.x * NSQ + s];
    uint4 q1 = Xr[(size_t)p1.x * NSQ + s];
    uint4 q2 = Xr[(size_t)p2.x * NSQ + s];
    uint4 q3 = Xr[(size_t)p3.x * NSQ + s];
    fma8(q0, __builtin_bit_cast(float, p0.y), acc);
    fma8(q1, __builtin_bit_cast(float, p1.y), acc);
    fma8(q2, __builtin_bit_cast(float, p2.y), acc);
    fma8(q3, __builtin_bit_cast(float, p3.y), acc);
  }
  for (; e < end; ++e) {
    uint2 p = pr[e];
    uint4 q = Xr[(size_t)p.x * NSQ + s];
    fma8(q, __builtin_bit_cast(float, p.y), acc);
  }
  uint4 o;
  o.x = (unsigned)f2bf(acc[0]) | ((unsigned)f2bf(acc[1]) << 16);
  o.y = (unsigned)f2bf(acc[2]) | ((unsigned)f2bf(acc[3]) << 16);
  o.z = (unsigned)f2bf(acc[4]) | ((unsigned)f2bf(acc[5]) << 16);
  o.w = (unsigned)f2bf(acc[6]) | ((unsigned)f2bf(acc[7]) << 16);
  reinterpret_cast<uint4*>(out)[(size_t)v * NSQ + s] = o;
}

// ---------------- bf16 MFMA GEMM: C[M,Nlog] = A[M,K](bf16) @ BT[Nlog,K](bf16)^T ----------------
__global__ __launch_bounds__(256) void k_gemm(const unsigned short* __restrict__ A,
                                              const unsigned short* __restrict__ BT,
                                              unsigned short* __restrict__ C, int M, int Nlog, int K) {
  constexpr int BM = 128, BN = 128, BK = 32;
  __shared__ unsigned short lA[(BK / 8) * BM * 8];
  __shared__ unsigned short lB[(BK / 8) * BN * 8];
  const int tid  = threadIdx.x;
  const int lane = tid & 63;
  const int wid  = tid >> 6;
  const int wr   = wid >> 1;
  const int wc   = wid & 1;
  const int m0 = blockIdx.x * BM;
  const int n0 = blockIdx.y * BN;

  const int sm  = tid >> 2;
  const int sk8 = tid & 3;
  const int fr = lane & 15, fq = lane >> 4;

  f32x4 acc[4][4] = {};

  for (int k0 = 0; k0 < K; k0 += BK) {
    uint4 a0, a1, b0, b1;
    {
      const uint4 z = make_uint4(0, 0, 0, 0);
      int r0 = m0 + sm, r1 = m0 + sm + 64;
      a0 = (r0 < M) ? *reinterpret_cast<const uint4*>(A + (size_t)r0 * K + k0 + sk8 * 8) : z;
      a1 = (r1 < M) ? *reinterpret_cast<const uint4*>(A + (size_t)r1 * K + k0 + sk8 * 8) : z;
      int c0 = n0 + sm, c1 = n0 + sm + 64;
      b0 = (c0 < Nlog) ? *reinterpret_cast<const uint4*>(BT + (size_t)c0 * K + k0 + sk8 * 8) : z;
      b1 = (c1 < Nlog) ? *reinterpret_cast<const uint4*>(BT + (size_t)c1 * K + k0 + sk8 * 8) : z;
    }
    __syncthreads();
    *reinterpret_cast<uint4*>(lA + (sk8 * BM + sm) * 8)      = a0;
    *reinterpret_cast<uint4*>(lA + (sk8 * BM + sm + 64) * 8) = a1;
    *reinterpret_cast<uint4*>(lB + (sk8 * BN + sm) * 8)      = b0;
    *reinterpret_cast<uint4*>(lB + (sk8 * BN + sm + 64) * 8) = b1;
    __syncthreads();

    bf16x8 af[4], bfr[4];
#pragma unroll
    for (int m = 0; m < 4; ++m)
      af[m] = *reinterpret_cast<const bf16x8*>(lA + (fq * BM + wr * 64 + m * 16 + fr) * 8);
#pragma unroll
    for (int nn = 0; nn < 4; ++nn)
      bfr[nn] = *reinterpret_cast<const bf16x8*>(lB + (fq * BN + wc * 64 + nn * 16 + fr) * 8);
#pragma unroll
    for (int m = 0; m < 4; ++m)
#pragma unroll
      for (int nn = 0; nn < 4; ++nn)
        acc[m][nn] = __builtin_amdgcn_mfma_f32_16x16x32_bf16(af[m], bfr[nn], acc[m][nn], 0, 0, 0);
  }

#pragma unroll
  for (int m = 0; m < 4; ++m) {
#pragma unroll
    for (int r = 0; r < 4; ++r) {
      int row = m0 + wr * 64 + m * 16 + fq * 4 + r;
      if (row >= M) continue;
#pragma unroll
      for (int nn = 0; nn < 4; ++nn) {
        int col = n0 + wc * 64 + nn * 16 + fr;
        if (col < Nlog)
          C[(size_t)row * Nlog + col] = f2bf(acc[m][nn][r]);
      }
    }
  }
}

// ---------------- BatchNorm ----------------
__global__ void k_bn_stats_bf16(const unsigned short* __restrict__ H, float* __restrict__ s1,
                                float* __restrict__ s2, int n, int C, int stride, int rpb) {
  int r0 = blockIdx.x * rpb;
  int r1 = r0 + rpb;
  if (r1 > n) r1 = n;
  for (int c = threadIdx.x; c < C; c += blockDim.x) {
    float a = 0.f, b = 0.f;
    for (int r = r0; r < r1; ++r) {
      float v = bf2f(H[(size_t)r * stride + c]);
      a += v;
      b = fmaf(v, v, b);
    }
    atomAddF(&s1[c], a);
    atomAddF(&s2[c], b);
  }
}

__global__ void k_bn_finalize(const float* __restrict__ s1, const float* __restrict__ s2,
                              const float* __restrict__ g, const float* __restrict__ beta,
                              float* __restrict__ scale, float* __restrict__ shift,
                              int C, float invN) {
  int c = blockIdx.x * blockDim.x + threadIdx.x;
  if (c >= C) return;
  float mean = s1[c] * invN;
  float var = fmaxf(s2[c] * invN - mean * mean, 0.f);
  float sc = g[c] * rsqrtf(var + kEps);
  scale[c] = sc;
  shift[c] = beta[c] - mean * sc;
}

// in-place BN+ReLU on bf16 buffer, 8 elems per thread. C power of 2.
template<int C>
__global__ void k_bn_apply_relu_bf16(unsigned short* __restrict__ H,
                                     const float* __restrict__ scale,
                                     const float* __restrict__ shift, int total8) {
  int i = blockIdx.x * blockDim.x + threadIdx.x;
  if (i >= total8) return;
  uint4 q = reinterpret_cast<uint4*>(H)[i];
  int c = (i * 8) & (C - 1);
  unsigned w[4] = {q.x, q.y, q.z, q.w};
  unsigned o[4];
#pragma unroll
  for (int j = 0; j < 4; ++j) {
    float lo = blo(w[j]);
    float hi = bhi(w[j]);
    int cl = c + j * 2;
    lo = fmaxf(fmaf(lo, scale[cl],     shift[cl]),     0.f);
    hi = fmaxf(fmaf(hi, scale[cl + 1], shift[cl + 1]), 0.f);
    o[j] = (unsigned)f2bf(lo) | ((unsigned)f2bf(hi) << 16);
  }
  reinterpret_cast<uint4*>(H)[i] = make_uint4(o[0], o[1], o[2], o[3]);
}

// ---------------- head: BN2-apply + relu + @Wl + bl + relu + log_softmax ----------------
__global__ __launch_bounds__(256) void k_head(const unsigned short* __restrict__ H,
    const float* __restrict__ scale, const float* __restrict__ shift,
    const float* __restrict__ Wl, const float* __restrict__ bl,
    float* __restrict__ out, int n) {
  __shared__ float sW[kH2 * kOut];
  __shared__ float sScale[kH2], sShift[kH2];
  for (int i = threadIdx.x; i < kH2 * kOut; i += blockDim.x) sW[i] = Wl[i];
  for (int i = threadIdx.x; i < kH2; i += blockDim.x) {
    sScale[i] = scale[i];
    sShift[i] = shift[i];
  }
  __syncthreads();
  float blv[kOut];
#pragma unroll
  for (int j = 0; j < kOut; ++j) blv[j] = bl[j];
  const int lane = threadIdx.x & 63;
  const int wid = (blockIdx.x * blockDim.x + threadIdx.x) >> 6;
  const int nw  = (gridDim.x * blockDim.x) >> 6;
  for (int node = wid; node < n; node += nw) {
    const unsigned short* hrow = H + (size_t)node * kH2p;
    float acc[kOut] = {};
    for (int k = lane; k < kH2; k += 64) {
      float v = fmaxf(fmaf(bf2f(hrow[k]), sScale[k], sShift[k]), 0.f);
      const float* wr = sW + k * kOut;
#pragma unroll
      for (int j = 0; j < kOut; ++j) acc[j] = fmaf(v, wr[j], acc[j]);
    }
#pragma unroll
    for (int j = 0; j < kOut; ++j) {
      float v = acc[j];
      for (int off = 32; off > 0; off >>= 1) v += __shfl_down(v, off);
      acc[j] = v;
    }
    if (lane == 0) {
      float vv[kOut], m = -1e30f;
#pragma unroll
      for (int j = 0; j < kOut; ++j) {
        vv[j] = fmaxf(acc[j] + blv[j], 0.f);
        m = fmaxf(m, vv[j]);
      }
      float s = 0.f;
#pragma unroll
      for (int j = 0; j < kOut; ++j) s += expf(vv[j] - m);
      float lse = m + logf(s);
      float* o = out + (size_t)node * kOut;
#pragma unroll
      for (int j = 0; j < kOut; ++j) o[j] = vv[j] - lse;
    }
  }
}

}  // namespace

extern "C" void kernel_launch(void* const* d_in, const int* in_sizes, int n_in,
                              void* d_out, int out_size, void* d_ws, size_t ws_size,
                              hipStream_t stream) {
  const float* x   = (const float*)d_in[0];
  const int*   ei  = (const int*)d_in[1];
  const float* ew  = (const float*)d_in[2];
  const float* W1  = (const float*)d_in[3];
  // d_in[4] = b1: constant per column -> cancelled by BN1 mean subtraction
  const float* g1  = (const float*)d_in[5];
  const float* be1 = (const float*)d_in[6];
  const float* W2  = (const float*)d_in[7];
  // d_in[8] = b2: cancelled by BN2
  const float* g2  = (const float*)d_in[9];
  const float* be2 = (const float*)d_in[10];
  const float* Wl  = (const float*)d_in[11];
  const float* bl  = (const float*)d_in[12];
  float* out = (float*)d_out;
  float* ws  = (float*)d_ws;

  const int n = in_sizes[0] / kIn;  // 50000
  const int e = in_sizes[1] / 2;    // 800000

  // workspace (float units), ~102 MB total:
  float* dis = ws;                                        // 50048
  int*   cnt = (int*)(ws + 50048);                        // 50048
  uint2* pr  = (uint2*)(ws + 100096);                     // 800000 pairs = 1.6M fl
  float* st  = ws + 1700096;                              // 4096
  float* s1a = st,        *s2a = st + 512,  *sc1 = st + 1024, *sh1 = st + 1536;
  float* s1b = st + 2048, *s2b = st + 2560, *sc2 = st + 3072, *sh2 = st + 3584;
  unsigned short* xbf = (unsigned short*)(ws + 1704192);  // N*128 bf16 = 3.2M fl
  unsigned short* W1T = (unsigned short*)(ws + 4904192);  // 512*128 bf16 = 32768 fl
  unsigned short* W2T = (unsigned short*)(ws + 4936960);  // 304*512 bf16 = 77824 fl
  unsigned short* slotA = (unsigned short*)(ws + 5014784);   // 7.6M fl: agg1 then t2
  unsigned short* slotB = (unsigned short*)(ws + 12614784);  // 12.8M fl: h1 then agg2
  unsigned short* agg1 = slotA;
  unsigned short* t2   = slotA;
  unsigned short* h1   = slotB;
  unsigned short* agg2 = slotB;

  constexpr int TPB = 256;

  // ---- CSC build + normalization + format prep ----
  k_init<<<(n + TPB - 1) / TPB, TPB, 0, stream>>>(dis, cnt, n);
  k_deg_cnt<<<(e + TPB - 1) / TPB, TPB, 0, stream>>>(dis, cnt, ei, ew, e);
  k_dis<<<(n + TPB - 1) / TPB, TPB, 0, stream>>>(dis, n);
  k_scan<<<1, 1024, 0, stream>>>(cnt, n);
  k_scatter<<<(e + TPB - 1) / TPB, TPB, 0, stream>>>(cnt, ei, ew, dis, pr, e);
  hipMemsetAsync(st, 0, 4096 * sizeof(float), stream);
  k_xbf<<<(n * (kIn / 4) + TPB - 1) / TPB, TPB, 0, stream>>>(x, xbf, n * (kIn / 4));
  k_wt<<<(kIn * kH1 + TPB - 1) / TPB, TPB, 0, stream>>>(W1, W1T, kIn, kH1, kH1);
  k_wt<<<(kH1 * kH2p + TPB - 1) / TPB, TPB, 0, stream>>>(W2, W2T, kH1, kH2, kH2p);

  // ---- layer 1: agg1 = A(xbf); h1 = bf16(agg1@W1); BN1 stats; in-place BN+ReLU ----
  {
    int tot = n * (kIn / 8);  // 16B granules
    k_gather<kIn / 8><<<(tot + TPB - 1) / TPB, TPB, 0, stream>>>(xbf, cnt, pr, dis, agg1, n);
  }
  {
    dim3 g((n + 127) / 128, kH1 / 128);
    k_gemm<<<g, 256, 0, stream>>>(agg1, W1T, h1, n, kH1, kIn);
  }
  k_bn_stats_bf16<<<512, 256, 0, stream>>>(h1, s1a, s2a, n, kH1, kH1, (n + 511) / 512);
  k_bn_finalize<<<(kH1 + 255) / 256, 256, 0, stream>>>(s1a, s2a, g1, be1, sc1, sh1, kH1, 1.0f / n);
  k_bn_apply_relu_bf16<kH1><<<((n * (kH1 / 8)) + TPB - 1) / TPB, TPB, 0, stream>>>(
      h1, sc1, sh1, n * (kH1 / 8));

  // ---- layer 2: t2 = bf16(h1@W2) [padded 304]; agg2 = A(t2); BN2 stats ----
  {
    dim3 g((n + 127) / 128, (kH2p + 127) / 128);
    k_gemm<<<g, 256, 0, stream>>>(h1, W2T, t2, n, kH2p, kH1);
  }
  {
    int tot = n * (kH2p / 8);
    k_gather<kH2p / 8><<<(tot + TPB - 1) / TPB, TPB, 0, stream>>>(t2, cnt, pr, dis, agg2, n);
  }
  k_bn_stats_bf16<<<512, 256, 0, stream>>>(agg2, s1b, s2b, n, kH2, kH2p, (n + 511) / 512);
  k_bn_finalize<<<(kH2 + 255) / 256, 256, 0, stream>>>(s1b, s2b, g2, be2, sc2, sh2, kH2, 1.0f / n);

  // ---- head ----
  k_head<<<1024, 256, 0, stream>>>(agg2, sc2, sh2, Wl, bl, out, n);
}